// Round 8
// baseline (160.771 us; speedup 1.0000x reference)
//
#include <hip/hip_runtime.h>

// LocallyConnected1d via bf16 MFMA: out[b,o,l] = sum_{i,k} x[b,i,l+k-4]*w[i,o,k,l] + bias[o,l]
// 512 per-l GEMMs (M=b, N=o (8 real, 8 zero-padded), K=576 k-major).
//
// R16: topology change (R9-R15 falsified: vmem latency/pacing, barrier
// semantics/count, bank conflicts, step count -- all null; per-step time
// 2.4x the sum of accounted pipes; the never-varied variable is the
// monolithic 1-block/CU layout: one barrier domain, zero placement slack).
//  * Block = 16 b x 16 l x 8 o: 256 thr (4 waves), LDS 48768 B ->
//    3 blocks/CU co-resident (146 KB of 160, real margin -- R11 lesson).
//    3 independent barrier domains interleave; 4 blocks/CU average
//    amortizes dispatch imbalance (+-25% not +-100%).
//  * grid 1024: idx = lt*32 + q*8 + os. The 4 b-siblings (q) of one
//    (lt,os) weight slice differ by 8: same XCD class, adjacent launch ->
//    they stream the same 288 KB w-slice concurrently, L2/MSHR merges,
//    HBM weight fetch stays ~once (watch FETCH_SIZE: ~85 MB pass,
//    ~290 MB = sharing failed). x over-read is L3-served (8.4 MB unique).
//  * Inner machinery carried verbatim from R15: asm ring loads + manual
//    WAITV (ledger rescaled: 4 loads/step -> steady WAITV(8), tail 4/0),
//    R12 ks-rotation, lgkm-only BAR.

#define CIN   64
#define COUT  64
#define SEQ   512
#define KS    9
#define LT    16
#define OT    8
#define LWIN  24
#define BB    16                       // b per block
#define WSTR  (COUT*KS*SEQ)            // weight i-stride (floats)
#define XBS   36                       // Xs b-stride (ush): 32 i + 4 pad (18-bank stride: 16 lanes -> 16 banks)
#define XLW   (BB*XBS)                 // Xs lw-stride = 576 ush
#define XS_ELEMS (LWIN*XLW)            // 13824 ush = 27648 B
#define BOS   40                       // Bs o-stride (ush)
#define BLS   328                      // Bs l-stride (ush)
#define BSLOT (LT*BLS)                 // 5248 ush per buffer
#define ZOFF  (XS_ELEMS + 2*BSLOT)     // 24320: zero region for n>=8 B reads
#define LDS_USH (ZOFF + 64)            // 24384 ush
#define LDS_BYTES (LDS_USH*2)          // 48768 B -> 3 blocks/CU
#define NSTEP 18                       // 2 i-halves x 9 k-taps

typedef __attribute__((ext_vector_type(8))) short bf16x8;
typedef __attribute__((ext_vector_type(4))) float f32x4;

__device__ __forceinline__ uint pack2bf(float a0, float a1) {
    uint u0 = __float_as_uint(a0) + 0x8000u;
    uint u1 = __float_as_uint(a1) + 0x8000u;
    return __builtin_amdgcn_perm(u1, u0, 0x07060302);  // (bf(a1)<<16)|bf(a0)
}

// Relaxed barrier: drain LDS only; asm ring loads stay in flight across it.
#define BAR() do {                                                           \
    asm volatile("s_waitcnt lgkmcnt(0)" ::: "memory");                       \
    __builtin_amdgcn_s_barrier();                                            \
    asm volatile("" ::: "memory");                                           \
} while (0)

// Manual counted vmem wait + sched_barrier(0) (rule #18: stop reg-only
// pack/ds_write hoisting above the wait).
#define WAITV(n) do {                                                        \
    asm volatile("s_waitcnt vmcnt(" #n ")" ::: "memory");                    \
    __builtin_amdgcn_sched_barrier(0);                                       \
} while (0)

__global__ __launch_bounds__(256, 3)
void lc1d_mfma(const float* __restrict__ x, const float* __restrict__ w,
               const float* __restrict__ bias, float* __restrict__ out)
{
    extern __shared__ ushort lds[];
    ushort* Xs = lds;                    // [lw 0..23][b 0..15][ks-rotated 32 + pad]
    ushort* BsB = lds + XS_ELEMS;        // 2 x [l 0..15][o 0..7][kk 0..31]

    const int tid  = threadIdx.x;
    const int lane = tid & 63;
    const int lg   = tid >> 6;           // wave id 0..3 = l-group
    const int lt = blockIdx.x >> 5;      // 0..31
    const int q  = (blockIdx.x >> 3) & 3;// b-quarter
    const int os = blockIdx.x & 7;       // 0..7 == XCD class
    const int l0 = lt * LT;
    const int o0 = os * OT;
    const int b0 = q * BB;

    // ---- weight stager mapping (all 256 threads): 64-B-contiguous l spans --
    const int lf  = tid & 3;             // float4 within the 16-l span
    const int oo  = (tid >> 2) & 7;      // o
    const int ipp = (tid >> 5) & 7;      // i-pair (2 groups: +0, +16)

    const float* wbase = w + ((size_t)(2*ipp)*COUT + (o0 + oo))*(KS*SEQ) + l0 + lf*4;

    f32x4 rA[3][2], rB[3][2];            // 3-slot ring x 2 i-pair groups

    // step s: ih = s/9, k = s%9. 4 asm loads/step (invisible to the
    // compiler's waitcnt pass -> no compiler vmem waits in the loop).
    #define LOAD_RING(sl, s) if ((s) < NSTEP) {                                  \
        const int ih_ = (s) / 9, k_ = (s) - 9*((s)/9);                           \
        const float* p0_ = wbase + (size_t)ih_*32*WSTR + k_*SEQ;                 \
        const float* p1_ = p0_ + WSTR;                                           \
        const float* p2_ = p0_ + 16*WSTR;                                        \
        const float* p3_ = p0_ + 17*WSTR;                                        \
        asm volatile("global_load_dwordx4 %0, %1, off"                           \
                     : "=&v"(rA[sl][0]) : "v"(p0_));                             \
        asm volatile("global_load_dwordx4 %0, %1, off"                           \
                     : "=&v"(rB[sl][0]) : "v"(p1_));                             \
        asm volatile("global_load_dwordx4 %0, %1, off"                           \
                     : "=&v"(rA[sl][1]) : "v"(p2_));                             \
        asm volatile("global_load_dwordx4 %0, %1, off"                           \
                     : "=&v"(rB[sl][1]) : "v"(p3_));                             \
    }

    // transpose+cvt ring slot -> Bs parity (s&1): kk = 2*ipp + g*16 (+0/1)
    #define WRITE_BS(sl, s) {                                                    \
        ushort* dst_ = BsB + ((s)&1)*BSLOT + oo*BOS + 2*ipp;                     \
        _Pragma("unroll")                                                        \
        for (int g = 0; g < 2; ++g) {                                            \
            _Pragma("unroll")                                                    \
            for (int dl = 0; dl < 4; ++dl) {                                     \
                uint pk_ = pack2bf(rA[sl][g][dl], rB[sl][g][dl]);                \
                *(uint*)(dst_ + g*16 + (lf*4+dl)*BLS) = pk_;                     \
            }                                                                    \
        }                                                                        \
    }

    // stage Xs for i-half ih: Xs[lw][b][rot(ii)] = bf16(x[b0+b, ih*32+ii, l0-4+lw])
    // rot (R12): row lw = qq*4+dl keeps its four 8-ush ks-groups rotated by
    // qq&3 = (row>>2)&3, matching the read-side col formula below.
    #define STAGE_XS(ih) {                                                       \
        const int qq  = tid & 7;                                                 \
        const int rp0 = tid >> 3;                                                \
        const int cr_ = (qq & 3) << 3;                                           \
        if (qq < 6) {                                                            \
            _Pragma("unroll")                                                    \
            for (int it = 0; it < 8; ++it) {                                     \
                const int rp = rp0 + it*32;                                      \
                const int b_ = rp >> 4, ip_ = rp & 15;                           \
                const float* s0 = x + ((size_t)((b0 + b_)*CIN) + (ih)*32         \
                                       + 2*ip_)*SEQ + (l0 - 4) + qq*4;           \
                float4 v0 = make_float4(0.f,0.f,0.f,0.f), v1 = v0;               \
                if (!((lt == 0 && qq == 0) || (lt == 31 && qq == 5))) {          \
                    v0 = *(const float4*)s0;                                     \
                    v1 = *(const float4*)(s0 + SEQ);                             \
                }                                                                \
                ushort* d_ = Xs + b_*XBS + ((2*ip_ + cr_) & 31);                 \
                _Pragma("unroll")                                                \
                for (int dl = 0; dl < 4; ++dl)                                   \
                    *(uint*)(d_ + (qq*4+dl)*XLW) = pack2bf((&v0.x)[dl],          \
                                                           (&v1.x)[dl]);         \
            }                                                                    \
        }                                                                        \
    }

    // MFMA lane constants
    const int abase = (lane & 15)*XBS;                 // 16 b rows, stride 18 banks
    const int ks_   = lane >> 4;
    const int boff  = (lane & 15)*BOS + ks_*8;
    const bool nhi  = (lane & 15) >= 8;                // dead o lanes -> zeros
    const ushort* zptr = lds + ZOFF + ks_*8;           // broadcast zeros

    f32x4 acc[4];
    #pragma unroll
    for (int j = 0; j < 4; ++j) acc[j] = (f32x4)0.0f;

    // gather-then-MFMA (one lgkm wait cluster)
    #define DO_MFMA(s) {                                                         \
        const int k_ = (s) % 9;                                                  \
        const ushort* BsS = BsB + ((s)&1)*BSLOT;                                 \
        bf16x8 Af[4], Bf[4];                                                     \
        _Pragma("unroll")                                                        \
        for (int dl = 0; dl < 4; ++dl) {                                         \
            const int ll  = lg*4 + dl;                                           \
            const int row = ll + k_;                                             \
            const int col = ((ks_ + (row >> 2)) & 3) << 3;                       \
            Af[dl] = *(const bf16x8*)(Xs + row*XLW + abase + col);               \
            Bf[dl] = *(const bf16x8*)(nhi ? zptr : (BsS + ll*BLS + boff));       \
        }                                                                        \
        _Pragma("unroll")                                                        \
        for (int dl = 0; dl < 4; ++dl)                                           \
            acc[dl] = __builtin_amdgcn_mfma_f32_16x16x32_bf16(Af[dl], Bf[dl],    \
                                                              acc[dl], 0, 0, 0); \
    }

    // one barrier per step; stagers fill Bs parity (s+1)&1 from the set
    // issued 3 steps ago, released by exactly vmcnt(wv) (4 loads/set).
    #define STEP(s, wv) {                                                        \
        if ((s) < NSTEP-1) {                                                     \
            WAITV(wv);                                                           \
            WRITE_BS(((s)+1)%3, (s)+1)                                           \
        }                                                                        \
        LOAD_RING(((s)+1)%3, (s)+4)                                              \
        DO_MFMA(s)                                                               \
        BAR();                                                                   \
    }

    // ---- prologue ----
    LOAD_RING(0, 0)
    LOAD_RING(1, 1)
    LOAD_RING(2, 2)
    if (tid < 64) lds[ZOFF + tid] = 0;
    STAGE_XS(0)
    WAITV(0);          // drain: x episode already drained ring (FIFO); safe
    WRITE_BS(0, 0)
    LOAD_RING(0, 3)
    BAR();             // Xs(ih0) + Bs(step0) + zero region ready

    STEP(0,8)  STEP(1,8)  STEP(2,8)  STEP(3,8)  STEP(4,8)
    STEP(5,8)  STEP(6,8)  STEP(7,8)  STEP(8,8)

    STAGE_XS(1)        // all half-0 Xs reads completed at STEP(8)'s barrier
    BAR();             // (compiler x-waits drain ring once: refill bubble only)

    STEP(9,8)   STEP(10,8) STEP(11,8) STEP(12,8) STEP(13,8)
    STEP(14,8)  STEP(15,4) STEP(16,0) STEP(17,0)

    // ---- epilogue: C col = o' = lane&15 (store only o'<8), row = b_local ----
    if (!nhi) {
        const int og = o0 + (lane & 15);
        const int rb = ks_*4;
        #pragma unroll
        for (int dl = 0; dl < 4; ++dl) {
            const int lgl = l0 + lg*4 + dl;
            const float bv = bias[og*SEQ + lgl];
            #pragma unroll
            for (int r = 0; r < 4; ++r) {
                const int bg = b0 + rb + r;
                out[((size_t)(bg*COUT + og))*SEQ + lgl] = acc[dl][r] + bv;
            }
        }
    }
}

extern "C" void kernel_launch(void* const* d_in, const int* in_sizes, int n_in,
                              void* d_out, int out_size, void* d_ws, size_t ws_size,
                              hipStream_t stream) {
    const float* x    = (const float*)d_in[0];
    const float* wgt  = (const float*)d_in[1];
    const float* bias = (const float*)d_in[2];
    float* out        = (float*)d_out;

    hipFuncSetAttribute((const void*)lc1d_mfma,
                        hipFuncAttributeMaxDynamicSharedMemorySize, LDS_BYTES);
    // idx = lt*32 + q*8 + os: q-siblings (same w slice) are 8 apart ->
    // same XCD class + adjacent launch -> L2-shared weight stream.
    dim3 grid(1024);
    lc1d_mfma<<<grid, 256, LDS_BYTES, stream>>>(x, wgt, bias, out);
}

// Round 9
// 158.220 us; speedup vs baseline: 1.0161x; 1.0161x over previous
//
#include <hip/hip_runtime.h>

// LocallyConnected1d via bf16 MFMA: out[b,o,l] = sum_{i,k} x[b,i,l+k-4]*w[i,o,k,l] + bias[o,l]
// 512 per-l GEMMs (M=b=64, N=o, K=576 k-major).
//
// R17: 16 REAL o per MFMA (R8-R16 all padded N to 16 with 8 zero columns:
// half of every MFMA and half of all B-fragment LDS reads were waste, and
// the 4 b-tile waves re-read identical B data). Re-tile:
//  * block = 64 b x 8 l x 16 o (LT=8, OT=16), grid 256 = 64 lt x 4 os,
//    1024 thr, 16 waves = 4 bt x 4 lg (2 l each), 18 steps as before.
//  * per step: 32 MFMAs (was 64), 64 KB LDS fragment reads (was 128 KB),
//    16 KB weight staging (same). Zero-region/nhi machinery deleted.
//  * conflict-free layouts re-derived: XBS=36 (16 b lanes -> 16 banks),
//    BOS=36 (16 o lanes -> 16 banks), XLW = 64*36+4 (stage rows on 4
//    bank-octants, uniform 2-way = free), R12 ks-rotation with exactly
//    4 qq <-> 4 rotations. Bs write: 32 (oo,ipp) lanes -> 32 banks, lf
//    2-way. LDS = 92288 B -> 1 block/CU.
//  * R10 machinery: 3-slot IR-load ring, lgkm-only BAR (R15's manual
//    vmcnt pacing reverted: proven neutral-to-harmful).

#define CIN   64
#define COUT  64
#define SEQ   512
#define KS    9
#define LT    8
#define OT    16
#define LWIN  16                       // LT + KS - 1
#define WSTR  (COUT*KS*SEQ)            // weight i-stride (floats)
#define XBS   36                       // Xs b-stride (ush): 32 i + 4 pad (stride 18 banks)
#define XLW   (64*XBS + 4)             // Xs row stride = 2308 ush (pad: rows hit 4 octants)
#define XS_ELEMS (LWIN*XLW)            // 36928 ush
#define BOS   36                       // Bs o-stride (ush): stride 18 banks
#define BLS   (OT*BOS)                 // Bs l-stride = 576 ush
#define BSLOT (LT*BLS)                 // 4608 ush per parity buffer
#define LDS_USH (XS_ELEMS + 2*BSLOT)   // 46144 ush
#define LDS_BYTES (LDS_USH*2)          // 92288 B -> 1 block/CU
#define NSTEP 18                       // 2 i-halves x 9 k-taps

typedef __attribute__((ext_vector_type(8))) short bf16x8;
typedef __attribute__((ext_vector_type(4))) float f32x4;

__device__ __forceinline__ uint pack2bf(float a0, float a1) {
    uint u0 = __float_as_uint(a0) + 0x8000u;
    uint u1 = __float_as_uint(a1) + 0x8000u;
    return __builtin_amdgcn_perm(u1, u0, 0x07060302);  // (bf(a1)<<16)|bf(a0)
}

// Relaxed barrier: drain LDS only; ring loads stay in flight across it.
#define BAR() do {                                                           \
    asm volatile("s_waitcnt lgkmcnt(0)" ::: "memory");                       \
    __builtin_amdgcn_s_barrier();                                            \
    asm volatile("" ::: "memory");                                           \
} while (0)

__global__ __launch_bounds__(1024, 4)
void lc1d_mfma(const float* __restrict__ x, const float* __restrict__ w,
               const float* __restrict__ bias, float* __restrict__ out)
{
    extern __shared__ ushort lds[];
    ushort* Xs = lds;                    // [lw 0..15][b 0..63][ks-rotated 32 + pad]
    ushort* BsB = lds + XS_ELEMS;        // 2 x [l 0..7][o 0..15][kk 0..31]

    const int tid  = threadIdx.x;
    const int lane = tid & 63;
    const int wvid = tid >> 6;           // 0..15
    const int bt = wvid & 3;             // wave's b-tile (16 b)
    const int lg = wvid >> 2;            // wave's l-group (2 l)
    const int lt = blockIdx.x >> 2;      // 0..63
    const int os = blockIdx.x & 3;       // o-slice
    const int l0 = lt * LT;
    const int o0 = os * OT;

    // ---- weight stager mapping (tid < 512): 32-B-contiguous l spans ----
    const bool stager = (tid < 512);
    const int lf  = tid & 1;             // float4 within the 8-l span
    const int oo  = (tid >> 1) & 15;     // o (16)
    const int ipp = (tid >> 5) & 15;     // i-pair within 32-i half

    const float* wbase = w + ((size_t)(2*ipp)*COUT + (o0 + oo))*(KS*SEQ) + l0 + lf*4;

    float4 rA[3], rB[3];                 // 3-slot ring, i-pair per slot

    // step s: ih = s/9 (i-half), k = s%9 (tap)
    #define LOAD_RING(sl, s) if (stager && (s) < NSTEP) {                        \
        const int ih_ = (s) / 9, k_ = (s) - 9*((s)/9);                           \
        const float* p_ = wbase + (size_t)ih_*32*WSTR + k_*SEQ;                  \
        rA[sl] = *(const float4*)p_;                                             \
        rB[sl] = *(const float4*)(p_ + WSTR);                                    \
    }

    // transpose+cvt ring slot -> Bs parity (s&1): b32 of i-pair at [l][o][kk]
    // banks: (oo,ipp) = 32 lanes -> 32 distinct banks; lf 2-way (free).
    #define WRITE_BS(sl, s) if (stager) {                                        \
        ushort* dst_ = BsB + ((s)&1)*BSLOT + oo*BOS + 2*ipp;                     \
        _Pragma("unroll")                                                        \
        for (int dl = 0; dl < 4; ++dl) {                                         \
            uint pk_ = pack2bf((&rA[sl].x)[dl], (&rB[sl].x)[dl]);                \
            *(uint*)(dst_ + (lf*4+dl)*BLS) = pk_;                                \
        }                                                                        \
    }

    // stage Xs for i-half ih: Xs[lw][b][rot(ii)] = bf16(x[b, ih*32+ii, l0-4+lw])
    // thread = (qq = l-quad 0..3, rp = (b, ii-pair)); 4 iters cover 64 b x 16 ip.
    // rot: row lw = qq*4+dl rotated by qq (= row>>2), matching read-side col.
    #define STAGE_XS(ih) {                                                       \
        const int qq  = tid & 3;                                                 \
        const int rp0 = tid >> 2;                                                \
        const int cr_ = qq << 3;                                                 \
        _Pragma("unroll")                                                        \
        for (int it = 0; it < 4; ++it) {                                         \
            const int rp = rp0 + it*256;                                         \
            const int b_ = rp >> 4, ip_ = rp & 15;                               \
            const float* s0 = x + ((size_t)(b_*CIN) + (ih)*32 + 2*ip_)*SEQ       \
                                + (l0 - 4) + qq*4;                               \
            float4 v0 = make_float4(0.f,0.f,0.f,0.f), v1 = v0;                   \
            if (!((lt == 0 && qq == 0) || (lt == 63 && qq == 3))) {              \
                v0 = *(const float4*)s0;                                         \
                v1 = *(const float4*)(s0 + SEQ);                                 \
            }                                                                    \
            ushort* d_ = Xs + b_*XBS + ((2*ip_ + cr_) & 31);                     \
            _Pragma("unroll")                                                    \
            for (int dl = 0; dl < 4; ++dl)                                       \
                *(uint*)(d_ + (qq*4+dl)*XLW) = pack2bf((&v0.x)[dl],              \
                                                       (&v1.x)[dl]);             \
        }                                                                        \
    }

    // MFMA lane constants (16 real o columns -- no zero lanes)
    const int abase = (bt*16 + (lane & 15))*XBS;
    const int ks_   = lane >> 4;
    const int boff  = (lane & 15)*BOS + ks_*8;

    f32x4 acc[2];
    acc[0] = (f32x4)0.0f;
    acc[1] = (f32x4)0.0f;

    #define DO_MFMA(s) {                                                         \
        const int k_ = (s) % 9;                                                  \
        const ushort* BsS = BsB + ((s)&1)*BSLOT;                                 \
        _Pragma("unroll")                                                        \
        for (int dl = 0; dl < 2; ++dl) {                                         \
            const int ll  = lg*2 + dl;                                           \
            const int row = ll + k_;                                             \
            const int col = ((ks_ + (row >> 2)) & 3) << 3;                       \
            bf16x8 Af = *(const bf16x8*)(Xs + row*XLW + abase + col);            \
            bf16x8 Bf = *(const bf16x8*)(BsS + ll*BLS + boff);                   \
            acc[dl] = __builtin_amdgcn_mfma_f32_16x16x32_bf16(Af, Bf, acc[dl],   \
                                                              0, 0, 0);          \
        }                                                                        \
    }

    // one barrier per step: during step s, stagers fill Bs parity (s+1)&1.
    #define STEP(s) {                                                            \
        if ((s) < NSTEP-1) WRITE_BS(((s)+1)%3, (s)+1)                            \
        LOAD_RING(((s)+1)%3, (s)+4)                                              \
        DO_MFMA(s)                                                               \
        BAR();                                                                   \
    }

    // ---- prologue ----
    LOAD_RING(0, 0)
    LOAD_RING(1, 1)
    LOAD_RING(2, 2)
    STAGE_XS(0)
    WRITE_BS(0, 0)
    LOAD_RING(0, 3)
    BAR();             // Xs(ih0) + Bs(step0) ready

    STEP(0)  STEP(1)  STEP(2)  STEP(3)  STEP(4)
    STEP(5)  STEP(6)  STEP(7)  STEP(8)

    STAGE_XS(1)        // all half-0 Xs reads completed at STEP(8)'s barrier
    BAR();

    STEP(9)  STEP(10) STEP(11) STEP(12) STEP(13)
    STEP(14) STEP(15) STEP(16) STEP(17)

    // ---- epilogue: C col = o' = lane&15 (all 16 real), row = b_local ----
    {
        const int og = o0 + (lane & 15);
        const int rb = ks_*4;
        #pragma unroll
        for (int dl = 0; dl < 2; ++dl) {
            const int lgl = l0 + lg*2 + dl;
            const float bv = bias[og*SEQ + lgl];
            #pragma unroll
            for (int r = 0; r < 4; ++r) {
                const int bg = bt*16 + rb + r;
                out[((size_t)(bg*COUT + og))*SEQ + lgl] = acc[dl][r] + bv;
            }
        }
    }
}

extern "C" void kernel_launch(void* const* d_in, const int* in_sizes, int n_in,
                              void* d_out, int out_size, void* d_ws, size_t ws_size,
                              hipStream_t stream) {
    const float* x    = (const float*)d_in[0];
    const float* wgt  = (const float*)d_in[1];
    const float* bias = (const float*)d_in[2];
    float* out        = (float*)d_out;

    hipFuncSetAttribute((const void*)lc1d_mfma,
                        hipFuncAttributeMaxDynamicSharedMemorySize, LDS_BYTES);
    dim3 grid(256);   // blockIdx = lt*4 + os
    lc1d_mfma<<<grid, 1024, LDS_BYTES, stream>>>(x, wgt, bias, out);
}